// Round 1
// baseline (941.676 us; speedup 1.0000x reference)
//
#include <hip/hip_runtime.h>
#include <hip/hip_bf16.h>
#include <math.h>

typedef float f32x4 __attribute__((ext_vector_type(4)));
typedef short bf16x8 __attribute__((ext_vector_type(8)));

#define NPAR 100000
#define NFIG 20000
#define NTAB 20000
#define NCIT 50000
#define NEDGE 200000
#define CAP 32

__device__ __forceinline__ unsigned short f2b(float f) {
    union { float f; unsigned u; } x; x.f = f;
    unsigned r = x.u + 0x7FFFu + ((x.u >> 16) & 1u);
    return (unsigned short)(r >> 16);
}
__device__ __forceinline__ float b2f(unsigned short b) {
    union { unsigned u; float f; } x; x.u = ((unsigned)b) << 16; return x.f;
}

// ---- transpose W [256,256] f32 row-major(k,n) -> WT bf16 [n][k] ----
__global__ void k_transpose_bf16(const float* __restrict__ W, unsigned short* __restrict__ WT) {
    int k = blockIdx.x, n = threadIdx.x;
    WT[n * 256 + k] = f2b(W[k * 256 + n]);
}

// ---- u = Wh_fig @ cls_w1, v = Wh_par @ cls_w2, Cpart = cls_b + bh terms ----
__global__ void k_precompute(const float* __restrict__ WhF, const float* __restrict__ bhF,
                             const float* __restrict__ WhP, const float* __restrict__ bhP,
                             const float* __restrict__ clsw, const float* __restrict__ clsb,
                             float* __restrict__ u, float* __restrict__ v, float* __restrict__ smallb) {
    int t = threadIdx.x;
    float su = 0.f, sv = 0.f;
    for (int j = 0; j < 128; ++j) {
        su += WhF[t * 128 + j] * clsw[j];
        sv += WhP[t * 128 + j] * clsw[128 + j];
    }
    u[t] = su; v[t] = sv;
    if (t == 0) {
        float c = clsb[0];
        for (int j = 0; j < 128; ++j) c += bhF[j] * clsw[j] + bhP[j] * clsw[128 + j];
        smallb[264] = c;  // Cpart
    }
}

// ---- projection GEMM: H = X @ W + b  (X f32 [N,256], WT bf16 [256,256], H bf16) ----
__global__ __launch_bounds__(256) void k_proj_gemm(const float* __restrict__ X,
                                                   const unsigned short* __restrict__ WT,
                                                   const float* __restrict__ bias,
                                                   unsigned short* __restrict__ Hout, int Nrows) {
    __shared__ unsigned short As[128][40];
    __shared__ unsigned short Bs[128][40];
    int t = threadIdx.x;
    int l = t & 63, w = t >> 6;
    int m0 = blockIdx.x * 128, n0 = blockIdx.y * 128;
    int wm = (w >> 1) * 64, wn = (w & 1) * 64;
    int lr = l & 15, lk = (l >> 4) * 8;
    f32x4 acc[4][4] = {};
    for (int k0 = 0; k0 < 256; k0 += 32) {
        for (int it = 0; it < 4; ++it) {   // stage A (f32 -> bf16)
            int m = it * 32 + (t >> 3), c = t & 7;
            int row = m0 + m;
            float4 xv = make_float4(0.f, 0.f, 0.f, 0.f);
            if (row < Nrows) xv = reinterpret_cast<const float4*>(X + (size_t)row * 256 + k0)[c];
            ushort4 bv; bv.x = f2b(xv.x); bv.y = f2b(xv.y); bv.z = f2b(xv.z); bv.w = f2b(xv.w);
            *reinterpret_cast<ushort4*>(&As[m][c * 4]) = bv;
        }
        for (int it = 0; it < 2; ++it) {   // stage B (bf16 direct)
            int n = it * 64 + (t >> 2), c = t & 3;
            uint4 wv = reinterpret_cast<const uint4*>(WT + (size_t)(n0 + n) * 256 + k0)[c];
            *reinterpret_cast<uint4*>(&Bs[n][c * 8]) = wv;
        }
        __syncthreads();
        bf16x8 af[4], bfr[4];
        for (int mm = 0; mm < 4; ++mm) af[mm] = *reinterpret_cast<const bf16x8*>(&As[wm + mm * 16 + lr][lk]);
        for (int nn = 0; nn < 4; ++nn) bfr[nn] = *reinterpret_cast<const bf16x8*>(&Bs[wn + nn * 16 + lr][lk]);
        for (int mm = 0; mm < 4; ++mm)
            for (int nn = 0; nn < 4; ++nn)
                acc[mm][nn] = __builtin_amdgcn_mfma_f32_16x16x32_bf16(af[mm], bfr[nn], acc[mm][nn], 0, 0, 0);
        __syncthreads();
    }
    for (int mm = 0; mm < 4; ++mm)
        for (int nn = 0; nn < 4; ++nn) {
            int col = n0 + wn + nn * 16 + lr;
            float bv = bias[col];
            for (int r = 0; r < 4; ++r) {
                int row = m0 + wm + mm * 16 + (l >> 4) * 4 + r;
                if (row < Nrows) Hout[(size_t)row * 256 + col] = f2b(acc[mm][nn][r] + bv);
            }
        }
}

// ---- kmean GEMM: colsum(tanh(R @ k_w + k_b)) -> atomicAdd into ksum[256] ----
__global__ __launch_bounds__(256) void k_kmean_gemm(const unsigned short* __restrict__ Rb,
                                                    const unsigned short* __restrict__ kwT,
                                                    const float* __restrict__ kb,
                                                    float* __restrict__ ksum, int Nrows) {
    __shared__ unsigned short As[128][40];
    __shared__ unsigned short Bs[128][40];
    int t = threadIdx.x;
    int l = t & 63, w = t >> 6;
    int m0 = blockIdx.x * 128, n0 = blockIdx.y * 128;
    int wm = (w >> 1) * 64, wn = (w & 1) * 64;
    int lr = l & 15, lk = (l >> 4) * 8;
    f32x4 acc[4][4] = {};
    for (int k0 = 0; k0 < 256; k0 += 32) {
        for (int it = 0; it < 2; ++it) {   // stage A (bf16 direct)
            int m = it * 64 + (t >> 2), c = t & 3;
            int row = m0 + m;
            uint4 rv = make_uint4(0u, 0u, 0u, 0u);
            if (row < Nrows) rv = reinterpret_cast<const uint4*>(Rb + (size_t)row * 256 + k0)[c];
            *reinterpret_cast<uint4*>(&As[m][c * 8]) = rv;
        }
        for (int it = 0; it < 2; ++it) {   // stage B
            int n = it * 64 + (t >> 2), c = t & 3;
            uint4 wv = reinterpret_cast<const uint4*>(kwT + (size_t)(n0 + n) * 256 + k0)[c];
            *reinterpret_cast<uint4*>(&Bs[n][c * 8]) = wv;
        }
        __syncthreads();
        bf16x8 af[4], bfr[4];
        for (int mm = 0; mm < 4; ++mm) af[mm] = *reinterpret_cast<const bf16x8*>(&As[wm + mm * 16 + lr][lk]);
        for (int nn = 0; nn < 4; ++nn) bfr[nn] = *reinterpret_cast<const bf16x8*>(&Bs[wn + nn * 16 + lr][lk]);
        for (int mm = 0; mm < 4; ++mm)
            for (int nn = 0; nn < 4; ++nn)
                acc[mm][nn] = __builtin_amdgcn_mfma_f32_16x16x32_bf16(af[mm], bfr[nn], acc[mm][nn], 0, 0, 0);
        __syncthreads();
    }
    for (int nn = 0; nn < 4; ++nn) {
        int col = n0 + wn + nn * 16 + lr;
        float kbv = kb[col];
        float cs = 0.f;
        for (int mm = 0; mm < 4; ++mm)
            for (int r = 0; r < 4; ++r) {
                int row = m0 + wm + mm * 16 + (l >> 4) * 4 + r;
                if (row < Nrows) cs += tanhf(acc[mm][nn][r] + kbv);
            }
        cs += __shfl_xor(cs, 16);
        cs += __shfl_xor(cs, 32);
        if ((l >> 4) == 0) atomicAdd(&ksum[col], cs);
    }
}

// ---- per-node attention dots: o[n,h] = sum_d H[n,h*32+d] * a[h*32+d], up to 4 vectors ----
__global__ void k_att(const unsigned short* __restrict__ Hb, int Nrows,
                      const float* __restrict__ a0, float* __restrict__ o0,
                      const float* __restrict__ a1, float* __restrict__ o1,
                      const float* __restrict__ a2, float* __restrict__ o2,
                      const float* __restrict__ a3, float* __restrict__ o3, int nv) {
    int w = threadIdx.x >> 6, l = threadIdx.x & 63;
    int row = blockIdx.x * 4 + w;
    if (row >= Nrows) return;
    ushort4 hv = *reinterpret_cast<const ushort4*>(&Hb[(size_t)row * 256 + l * 4]);
    float h0 = b2f(hv.x), h1 = b2f(hv.y), h2 = b2f(hv.z), h3 = b2f(hv.w);
    int e0 = l * 4;
#define ATT_DOT(A, O) { \
        float s = h0 * A[e0] + h1 * A[e0 + 1] + h2 * A[e0 + 2] + h3 * A[e0 + 3]; \
        s += __shfl_xor(s, 1); s += __shfl_xor(s, 2); s += __shfl_xor(s, 4); \
        if ((l & 7) == 0) O[row * 8 + (l >> 3)] = s; }
    ATT_DOT(a0, o0);
    if (nv > 1) ATT_DOT(a1, o1);
    if (nv > 2) ATT_DOT(a2, o2);
    if (nv > 3) ATT_DOT(a3, o3);
#undef ATT_DOT
}

// ---- bucket edges by dst ----
__global__ void k_bucket(const int* __restrict__ dst, int* __restrict__ count, int* __restrict__ elist) {
    int e = blockIdx.x * 256 + threadIdx.x;
    if (e >= NEDGE) return;
    int d = dst[e];
    int slot = atomicAdd(&count[d], 1);
    if (slot < CAP) elist[d * CAP + slot] = e;
}

// ---- per-dst aggregation (one wave per dst): r = relu((sum ex*xs)/(sum ex + eps)); g = r . v ----
__global__ void k_gather(const int* __restrict__ src, const int* __restrict__ count,
                         const int* __restrict__ elist, const unsigned short* __restrict__ Hsrc,
                         const float* __restrict__ as_, const float* __restrict__ ad_,
                         unsigned short* __restrict__ Rout, const float* __restrict__ v,
                         float* __restrict__ gout, int Ndst) {
    int w = threadIdx.x >> 6, l = threadIdx.x & 63;
    int d = blockIdx.x * 4 + w;
    if (d >= Ndst) return;
    int h = l >> 3;
    float adh = ad_[d * 8 + h];
    int cnt = count[d]; if (cnt > CAP) cnt = CAP;
    float a0 = 0.f, a1 = 0.f, a2 = 0.f, a3 = 0.f, den = 0.f;
    for (int i = 0; i < cnt; ++i) {
        int e = elist[d * CAP + i];
        int s = src[e];
        float al = as_[s * 8 + h] + adh;
        al = al > 0.f ? al : 0.2f * al;
        float ex = __expf(al);
        den += ex;
        ushort4 hv = *reinterpret_cast<const ushort4*>(&Hsrc[(size_t)s * 256 + l * 4]);
        a0 += ex * b2f(hv.x); a1 += ex * b2f(hv.y); a2 += ex * b2f(hv.z); a3 += ex * b2f(hv.w);
    }
    float inv = 1.0f / (den + 1e-16f);
    float r0 = fmaxf(a0 * inv, 0.f), r1 = fmaxf(a1 * inv, 0.f);
    float r2 = fmaxf(a2 * inv, 0.f), r3 = fmaxf(a3 * inv, 0.f);
    ushort4 rv; rv.x = f2b(r0); rv.y = f2b(r1); rv.z = f2b(r2); rv.w = f2b(r3);
    *reinterpret_cast<ushort4*>(&Rout[(size_t)d * 256 + l * 4]) = rv;
    float gs = r0 * v[l * 4] + r1 * v[l * 4 + 1] + r2 * v[l * 4 + 2] + r3 * v[l * 4 + 3];
    gs += __shfl_xor(gs, 1); gs += __shfl_xor(gs, 2); gs += __shfl_xor(gs, 4);
    gs += __shfl_xor(gs, 8); gs += __shfl_xor(gs, 16); gs += __shfl_xor(gs, 32);
    if (l == 0) gout[d] = gs;
}

// ---- pf metapath restricted to edges with dst == target ----
__global__ void k_pf_target(const int* __restrict__ psrc, const int* __restrict__ pdst,
                            const int* __restrict__ tgtp, const unsigned short* __restrict__ Hpar,
                            const float* __restrict__ as_pf, const float* __restrict__ ad_pf,
                            float* __restrict__ smallb) {
    int tgt = tgtp[0];
    int stride = gridDim.x * blockDim.x;
    for (int e = blockIdx.x * blockDim.x + threadIdx.x; e < NEDGE; e += stride) {
        if (pdst[e] != tgt) continue;
        int s = psrc[e];
        float ex[8];
#pragma unroll
        for (int h = 0; h < 8; ++h) {
            float al = as_pf[s * 8 + h] + ad_pf[tgt * 8 + h];
            al = al > 0.f ? al : 0.2f * al;
            ex[h] = __expf(al);
            atomicAdd(&smallb[256 + h], ex[h]);
        }
#pragma unroll
        for (int c = 0; c < 256; ++c)
            atomicAdd(&smallb[c], ex[c >> 5] * b2f(Hpar[(size_t)s * 256 + c]));
    }
}

// ---- semantic attention softmax + scalar C ----
__global__ void k_finalize(const float* __restrict__ kacc, const float* __restrict__ q,
                           const float* __restrict__ u, float* __restrict__ smallb) {
    __shared__ float red[256];
    __shared__ float sm[3];
    int t = threadIdx.x;
    float qv = q[t];
    for (int m = 0; m < 3; ++m) {
        red[t] = kacc[m * 256 + t] * qv;
        __syncthreads();
        for (int s = 128; s > 0; s >>= 1) { if (t < s) red[t] += red[t + s]; __syncthreads(); }
        if (t == 0) sm[m] = red[0] / (float)NPAR;
        __syncthreads();
    }
    float den = smallb[256 + (t >> 5)];
    float rt = fmaxf(smallb[t] / (den + 1e-16f), 0.f);
    red[t] = rt * u[t];
    __syncthreads();
    for (int s = 128; s > 0; s >>= 1) { if (t < s) red[t] += red[t + s]; __syncthreads(); }
    if (t == 0) {
        float mx = fmaxf(sm[0], fmaxf(sm[1], sm[2]));
        float e0 = expf(sm[0] - mx), e1 = expf(sm[1] - mx), e2 = expf(sm[2] - mx);
        float sd = e0 + e1 + e2;
        smallb[265] = e0 / sd; smallb[266] = e1 / sd; smallb[267] = e2 / sd;
        smallb[268] = red[0] + smallb[264];  // C
    }
}

// ---- final scores ----
__global__ void k_scores(const float* __restrict__ g, const float* __restrict__ smallb,
                         float* __restrict__ out) {
    int i = blockIdx.x * 256 + threadIdx.x;
    if (i >= NPAR) return;
    out[i] = smallb[268] + smallb[265] * g[i] + smallb[266] * g[NPAR + i] + smallb[267] * g[2 * NPAR + i];
}

extern "C" void kernel_launch(void* const* d_in, const int* in_sizes, int n_in,
                              void* d_out, int out_size, void* d_ws, size_t ws_size,
                              hipStream_t stream) {
    char* base = (char*)d_ws;
    size_t off = 0;
    auto alloc = [&](size_t b) -> void* { void* p = base + off; off += (b + 255) & ~(size_t)255; return p; };

    unsigned short* h_par = (unsigned short*)alloc((size_t)NPAR * 256 * 2);
    unsigned short* h_fig = (unsigned short*)alloc((size_t)NFIG * 256 * 2);
    unsigned short* h_tab = (unsigned short*)alloc((size_t)NTAB * 256 * 2);
    unsigned short* h_cit = (unsigned short*)alloc((size_t)NCIT * 256 * 2);
    unsigned short* r_buf = (unsigned short*)alloc((size_t)NPAR * 256 * 2);
    unsigned short* WT_par = (unsigned short*)alloc(256 * 256 * 2);
    unsigned short* WT_fig = (unsigned short*)alloc(256 * 256 * 2);
    unsigned short* WT_tab = (unsigned short*)alloc(256 * 256 * 2);
    unsigned short* WT_cit = (unsigned short*)alloc(256 * 256 * 2);
    unsigned short* kwT    = (unsigned short*)alloc(256 * 256 * 2);
    float* as_pf = (float*)alloc((size_t)NPAR * 8 * 4);
    float* ad_fp = (float*)alloc((size_t)NPAR * 8 * 4);
    float* ad_tp = (float*)alloc((size_t)NPAR * 8 * 4);
    float* ad_cp = (float*)alloc((size_t)NPAR * 8 * 4);
    float* as_fp = (float*)alloc((size_t)NFIG * 8 * 4);
    float* ad_pf = (float*)alloc((size_t)NFIG * 8 * 4);
    float* as_tp = (float*)alloc((size_t)NTAB * 8 * 4);
    float* as_cp = (float*)alloc((size_t)NCIT * 8 * 4);
    float* gbuf  = (float*)alloc((size_t)3 * NPAR * 4);
    int* count   = (int*)alloc((size_t)NPAR * 4);
    int* elist   = (int*)alloc((size_t)NPAR * CAP * 4);
    float* kacc  = (float*)alloc(3 * 256 * 4);
    float* uvec  = (float*)alloc(256 * 4);
    float* vvec  = (float*)alloc(256 * 4);
    float* smallb = (float*)alloc(512 * 4);

    hipMemsetAsync(kacc, 0, 3 * 256 * 4, stream);
    hipMemsetAsync(smallb, 0, 512 * 4, stream);

    k_transpose_bf16<<<256, 256, 0, stream>>>((const float*)d_in[4],  WT_par);
    k_transpose_bf16<<<256, 256, 0, stream>>>((const float*)d_in[6],  WT_fig);
    k_transpose_bf16<<<256, 256, 0, stream>>>((const float*)d_in[8],  WT_tab);
    k_transpose_bf16<<<256, 256, 0, stream>>>((const float*)d_in[10], WT_cit);
    k_transpose_bf16<<<256, 256, 0, stream>>>((const float*)d_in[24], kwT);

    k_precompute<<<1, 256, 0, stream>>>((const float*)d_in[29], (const float*)d_in[30],
                                        (const float*)d_in[27], (const float*)d_in[28],
                                        (const float*)d_in[35], (const float*)d_in[36],
                                        uvec, vvec, smallb);

    k_proj_gemm<<<dim3(782, 2), 256, 0, stream>>>((const float*)d_in[0], WT_par, (const float*)d_in[5],  h_par, NPAR);
    k_proj_gemm<<<dim3(157, 2), 256, 0, stream>>>((const float*)d_in[1], WT_fig, (const float*)d_in[7],  h_fig, NFIG);
    k_proj_gemm<<<dim3(157, 2), 256, 0, stream>>>((const float*)d_in[2], WT_tab, (const float*)d_in[9],  h_tab, NTAB);
    k_proj_gemm<<<dim3(391, 2), 256, 0, stream>>>((const float*)d_in[3], WT_cit, (const float*)d_in[11], h_cit, NCIT);

    k_att<<<25000, 256, 0, stream>>>(h_par, NPAR,
                                     (const float*)d_in[12], as_pf, (const float*)d_in[15], ad_fp,
                                     (const float*)d_in[19], ad_tp, (const float*)d_in[23], ad_cp, 4);
    k_att<<<5000, 256, 0, stream>>>(h_fig, NFIG,
                                    (const float*)d_in[14], as_fp, (const float*)d_in[13], ad_pf,
                                    nullptr, nullptr, nullptr, nullptr, 2);
    k_att<<<5000, 256, 0, stream>>>(h_tab, NTAB,
                                    (const float*)d_in[18], as_tp, nullptr, nullptr,
                                    nullptr, nullptr, nullptr, nullptr, 1);
    k_att<<<12500, 256, 0, stream>>>(h_cit, NCIT,
                                     (const float*)d_in[22], as_cp, nullptr, nullptr,
                                     nullptr, nullptr, nullptr, nullptr, 1);

    k_pf_target<<<256, 256, 0, stream>>>((const int*)d_in[37], (const int*)d_in[38], (const int*)d_in[49],
                                         h_par, as_pf, ad_pf, smallb);

    const int* srcs[3] = { (const int*)d_in[39], (const int*)d_in[43], (const int*)d_in[47] };
    const int* dsts[3] = { (const int*)d_in[40], (const int*)d_in[44], (const int*)d_in[48] };
    const unsigned short* hsrcs[3] = { h_fig, h_tab, h_cit };
    const float* ass[3] = { as_fp, as_tp, as_cp };
    const float* ads[3] = { ad_fp, ad_tp, ad_cp };
    for (int m = 0; m < 3; ++m) {
        hipMemsetAsync(count, 0, (size_t)NPAR * 4, stream);
        k_bucket<<<(NEDGE + 255) / 256, 256, 0, stream>>>(dsts[m], count, elist);
        k_gather<<<25000, 256, 0, stream>>>(srcs[m], count, elist, hsrcs[m], ass[m], ads[m],
                                            r_buf, vvec, gbuf + (size_t)m * NPAR, NPAR);
        k_kmean_gemm<<<dim3(782, 2), 256, 0, stream>>>(r_buf, kwT, (const float*)d_in[25],
                                                       kacc + m * 256, NPAR);
    }

    k_finalize<<<1, 256, 0, stream>>>(kacc, (const float*)d_in[26], uvec, smallb);
    k_scores<<<391, 256, 0, stream>>>(gbuf, smallb, (float*)d_out);
}

// Round 2
// 732.747 us; speedup vs baseline: 1.2851x; 1.2851x over previous
//
#include <hip/hip_runtime.h>
#include <hip/hip_bf16.h>
#include <math.h>

typedef float f32x4 __attribute__((ext_vector_type(4)));
typedef short bf16x8 __attribute__((ext_vector_type(8)));

#define NPAR 100000
#define NFIG 20000
#define NTAB 20000
#define NCIT 50000
#define NEDGE 200000
#define CAP 32
#define MPAD 100096   // 782*128

__device__ __forceinline__ unsigned short f2b(float f) {
    union { float f; unsigned u; } x; x.f = f;
    unsigned r = x.u + 0x7FFFu + ((x.u >> 16) & 1u);
    return (unsigned short)(r >> 16);
}
__device__ __forceinline__ float b2f(unsigned short b) {
    union { unsigned u; float f; } x; x.u = ((unsigned)b) << 16; return x.f;
}
__device__ __forceinline__ float fast_tanh(float x) {
    float e = __expf(2.f * x);
    return 1.f - 2.f * __builtin_amdgcn_rcpf(e + 1.f);
}
__device__ __forceinline__ void async_copy16(const unsigned short* g, unsigned short* l) {
    __builtin_amdgcn_global_load_lds(
        (const __attribute__((address_space(1))) unsigned int*)g,
        (__attribute__((address_space(3))) unsigned int*)l, 16, 0, 0);
}

// ---- f32 -> bf16 convert (vectorized, grid-stride) ----
__global__ void k_cvt(const float* __restrict__ X, unsigned short* __restrict__ Y, int n4) {
    int i = blockIdx.x * 256 + threadIdx.x;
    int stride = gridDim.x * 256;
    for (; i < n4; i += stride) {
        float4 v = reinterpret_cast<const float4*>(X)[i];
        ushort4 o; o.x = f2b(v.x); o.y = f2b(v.y); o.z = f2b(v.z); o.w = f2b(v.w);
        reinterpret_cast<ushort4*>(Y)[i] = o;
    }
}

// ---- transpose W [256,256] f32 row-major(k,n) -> WT bf16 [n][k] ----
__global__ void k_transpose_bf16(const float* __restrict__ W, unsigned short* __restrict__ WT) {
    int k = blockIdx.x, n = threadIdx.x;
    WT[n * 256 + k] = f2b(W[k * 256 + n]);
}

// ---- u = Wh_fig @ cls_w1, v = Wh_par @ cls_w2, Cpart ----
__global__ void k_precompute(const float* __restrict__ WhF, const float* __restrict__ bhF,
                             const float* __restrict__ WhP, const float* __restrict__ bhP,
                             const float* __restrict__ clsw, const float* __restrict__ clsb,
                             float* __restrict__ u, float* __restrict__ v, float* __restrict__ smallb) {
    int t = threadIdx.x;
    float su = 0.f, sv = 0.f;
    for (int j = 0; j < 128; ++j) {
        su += WhF[t * 128 + j] * clsw[j];
        sv += WhP[t * 128 + j] * clsw[128 + j];
    }
    u[t] = su; v[t] = sv;
    if (t == 0) {
        float c = clsb[0];
        for (int j = 0; j < 128; ++j) c += bhF[j] * clsw[j] + bhP[j] * clsw[128 + j];
        smallb[264] = c;
    }
}

// ---- unified bf16 GEMM, m97-style: global_load_lds + dbuf LDS + 1 barrier/K-step ----
// A [Mpad,256] bf16, B [n][k] bf16 256x256. mode 0: Hout=f2b(acc+bias); mode 1: ksum[col] += tanh(acc+bias) colsum
__global__ __launch_bounds__(256) void k_gemm_bf16(const unsigned short* __restrict__ A,
                                                   const unsigned short* __restrict__ B,
                                                   const float* __restrict__ bias,
                                                   unsigned short* __restrict__ Hout,
                                                   float* __restrict__ ksum,
                                                   int Nrows, int mode) {
    __shared__ __align__(16) unsigned short As[2][128 * 32];
    __shared__ __align__(16) unsigned short Bs[2][128 * 32];
    int t = threadIdx.x, l = t & 63, w = t >> 6;
    int n0 = blockIdx.x * 128, m0 = blockIdx.y * 128;
    int wm = (w >> 1) * 64, wn = (w & 1) * 64;
    int lr = l & 15, hi = l >> 4;
    int srow = l >> 2;          // 0..15 within 16-row chunk
    int scol = (l & 3) * 8;     // element offset within 32-elem (64B) row
    f32x4 acc[4][4] = {};

    const unsigned short* Abase = A + (size_t)m0 * 256;
    const unsigned short* Bbase = B + (size_t)n0 * 256;

    auto stage = [&](int buf, int k0) {
#pragma unroll
        for (int c = 0; c < 2; ++c) {
            int ci = w * 2 + c;   // 8 chunks of 16 rows x 64B
            async_copy16(Abase + (size_t)(ci * 16 + srow) * 256 + k0 + scol, &As[buf][ci * 512]);
            async_copy16(Bbase + (size_t)(ci * 16 + srow) * 256 + k0 + scol, &Bs[buf][ci * 512]);
        }
    };

    stage(0, 0);
    __syncthreads();
    int cur = 0;
    for (int ks = 0; ks < 8; ++ks) {
        if (ks < 7) stage(cur ^ 1, (ks + 1) * 32);
        bf16x8 af[4], bfr[4];
#pragma unroll
        for (int mm = 0; mm < 4; ++mm)
            af[mm] = *reinterpret_cast<const bf16x8*>(&As[cur][(wm + mm * 16 + lr) * 32 + hi * 8]);
#pragma unroll
        for (int nn = 0; nn < 4; ++nn)
            bfr[nn] = *reinterpret_cast<const bf16x8*>(&Bs[cur][(wn + nn * 16 + lr) * 32 + hi * 8]);
#pragma unroll
        for (int mm = 0; mm < 4; ++mm)
#pragma unroll
            for (int nn = 0; nn < 4; ++nn)
                acc[mm][nn] = __builtin_amdgcn_mfma_f32_16x16x32_bf16(af[mm], bfr[nn], acc[mm][nn], 0, 0, 0);
        __syncthreads();
        cur ^= 1;
    }

    if (mode == 0) {
#pragma unroll
        for (int mm = 0; mm < 4; ++mm)
#pragma unroll
            for (int nn = 0; nn < 4; ++nn) {
                int col = n0 + wn + nn * 16 + lr;
                float bv = bias[col];
#pragma unroll
                for (int r = 0; r < 4; ++r) {
                    int row = m0 + wm + mm * 16 + hi * 4 + r;
                    if (row < Nrows) Hout[(size_t)row * 256 + col] = f2b(acc[mm][nn][r] + bv);
                }
            }
    } else {
#pragma unroll
        for (int nn = 0; nn < 4; ++nn) {
            int col = n0 + wn + nn * 16 + lr;
            float kbv = bias[col];
            float cs = 0.f;
#pragma unroll
            for (int mm = 0; mm < 4; ++mm)
#pragma unroll
                for (int r = 0; r < 4; ++r) {
                    int row = m0 + wm + mm * 16 + hi * 4 + r;
                    if (row < Nrows) cs += fast_tanh(acc[mm][nn][r] + kbv);
                }
            cs += __shfl_xor(cs, 16);
            cs += __shfl_xor(cs, 32);
            if (hi == 0) atomicAdd(&ksum[col], cs);
        }
    }
}

// ---- per-node attention dots ----
__global__ void k_att(const unsigned short* __restrict__ Hb, int Nrows,
                      const float* __restrict__ a0, float* __restrict__ o0,
                      const float* __restrict__ a1, float* __restrict__ o1,
                      const float* __restrict__ a2, float* __restrict__ o2,
                      const float* __restrict__ a3, float* __restrict__ o3, int nv) {
    int w = threadIdx.x >> 6, l = threadIdx.x & 63;
    int row = blockIdx.x * 4 + w;
    if (row >= Nrows) return;
    ushort4 hv = *reinterpret_cast<const ushort4*>(&Hb[(size_t)row * 256 + l * 4]);
    float h0 = b2f(hv.x), h1 = b2f(hv.y), h2 = b2f(hv.z), h3 = b2f(hv.w);
    int e0 = l * 4;
#define ATT_DOT(A, O) { \
        float s = h0 * A[e0] + h1 * A[e0 + 1] + h2 * A[e0 + 2] + h3 * A[e0 + 3]; \
        s += __shfl_xor(s, 1); s += __shfl_xor(s, 2); s += __shfl_xor(s, 4); \
        if ((l & 7) == 0) O[row * 8 + (l >> 3)] = s; }
    ATT_DOT(a0, o0);
    if (nv > 1) ATT_DOT(a1, o1);
    if (nv > 2) ATT_DOT(a2, o2);
    if (nv > 3) ATT_DOT(a3, o3);
#undef ATT_DOT
}

// ---- bucket edges by dst ----
__global__ void k_bucket(const int* __restrict__ dst, int* __restrict__ count, int* __restrict__ elist) {
    int e = blockIdx.x * 256 + threadIdx.x;
    if (e >= NEDGE) return;
    int d = dst[e];
    int slot = atomicAdd(&count[d], 1);
    if (slot < CAP) elist[d * CAP + slot] = e;
}

// ---- per-dst aggregation ----
__global__ void k_gather(const int* __restrict__ src, const int* __restrict__ count,
                         const int* __restrict__ elist, const unsigned short* __restrict__ Hsrc,
                         const float* __restrict__ as_, const float* __restrict__ ad_,
                         unsigned short* __restrict__ Rout, const float* __restrict__ v,
                         float* __restrict__ gout, int Ndst) {
    int w = threadIdx.x >> 6, l = threadIdx.x & 63;
    int d = blockIdx.x * 4 + w;
    if (d >= Ndst) return;
    int h = l >> 3;
    float adh = ad_[d * 8 + h];
    int cnt = count[d]; if (cnt > CAP) cnt = CAP;
    float a0 = 0.f, a1 = 0.f, a2 = 0.f, a3 = 0.f, den = 0.f;
    for (int i = 0; i < cnt; ++i) {
        int e = elist[d * CAP + i];
        int s = src[e];
        float al = as_[s * 8 + h] + adh;
        al = al > 0.f ? al : 0.2f * al;
        float ex = __expf(al);
        den += ex;
        ushort4 hv = *reinterpret_cast<const ushort4*>(&Hsrc[(size_t)s * 256 + l * 4]);
        a0 += ex * b2f(hv.x); a1 += ex * b2f(hv.y); a2 += ex * b2f(hv.z); a3 += ex * b2f(hv.w);
    }
    float inv = 1.0f / (den + 1e-16f);
    float r0 = fmaxf(a0 * inv, 0.f), r1 = fmaxf(a1 * inv, 0.f);
    float r2 = fmaxf(a2 * inv, 0.f), r3 = fmaxf(a3 * inv, 0.f);
    ushort4 rv; rv.x = f2b(r0); rv.y = f2b(r1); rv.z = f2b(r2); rv.w = f2b(r3);
    *reinterpret_cast<ushort4*>(&Rout[(size_t)d * 256 + l * 4]) = rv;
    float gs = r0 * v[l * 4] + r1 * v[l * 4 + 1] + r2 * v[l * 4 + 2] + r3 * v[l * 4 + 3];
    gs += __shfl_xor(gs, 1); gs += __shfl_xor(gs, 2); gs += __shfl_xor(gs, 4);
    gs += __shfl_xor(gs, 8); gs += __shfl_xor(gs, 16); gs += __shfl_xor(gs, 32);
    if (l == 0) gout[d] = gs;
}

// ---- pf metapath restricted to target dst ----
__global__ void k_pf_target(const int* __restrict__ psrc, const int* __restrict__ pdst,
                            const int* __restrict__ tgtp, const unsigned short* __restrict__ Hpar,
                            const float* __restrict__ as_pf, const float* __restrict__ ad_pf,
                            float* __restrict__ smallb) {
    int tgt = tgtp[0];
    int stride = gridDim.x * blockDim.x;
    for (int e = blockIdx.x * blockDim.x + threadIdx.x; e < NEDGE; e += stride) {
        if (pdst[e] != tgt) continue;
        int s = psrc[e];
        float ex[8];
#pragma unroll
        for (int h = 0; h < 8; ++h) {
            float al = as_pf[s * 8 + h] + ad_pf[tgt * 8 + h];
            al = al > 0.f ? al : 0.2f * al;
            ex[h] = __expf(al);
            atomicAdd(&smallb[256 + h], ex[h]);
        }
#pragma unroll
        for (int c = 0; c < 256; ++c)
            atomicAdd(&smallb[c], ex[c >> 5] * b2f(Hpar[(size_t)s * 256 + c]));
    }
}

// ---- semantic attention softmax + scalar C ----
__global__ void k_finalize(const float* __restrict__ kacc, const float* __restrict__ q,
                           const float* __restrict__ u, float* __restrict__ smallb) {
    __shared__ float red[256];
    __shared__ float sm[3];
    int t = threadIdx.x;
    float qv = q[t];
    for (int m = 0; m < 3; ++m) {
        red[t] = kacc[m * 256 + t] * qv;
        __syncthreads();
        for (int s = 128; s > 0; s >>= 1) { if (t < s) red[t] += red[t + s]; __syncthreads(); }
        if (t == 0) sm[m] = red[0] / (float)NPAR;
        __syncthreads();
    }
    float den = smallb[256 + (t >> 5)];
    float rt = fmaxf(smallb[t] / (den + 1e-16f), 0.f);
    red[t] = rt * u[t];
    __syncthreads();
    for (int s = 128; s > 0; s >>= 1) { if (t < s) red[t] += red[t + s]; __syncthreads(); }
    if (t == 0) {
        float mx = fmaxf(sm[0], fmaxf(sm[1], sm[2]));
        float e0 = expf(sm[0] - mx), e1 = expf(sm[1] - mx), e2 = expf(sm[2] - mx);
        float sd = e0 + e1 + e2;
        smallb[265] = e0 / sd; smallb[266] = e1 / sd; smallb[267] = e2 / sd;
        smallb[268] = red[0] + smallb[264];
    }
}

// ---- final scores ----
__global__ void k_scores(const float* __restrict__ g, const float* __restrict__ smallb,
                         float* __restrict__ out) {
    int i = blockIdx.x * 256 + threadIdx.x;
    if (i >= NPAR) return;
    out[i] = smallb[268] + smallb[265] * g[i] + smallb[266] * g[NPAR + i] + smallb[267] * g[2 * NPAR + i];
}

extern "C" void kernel_launch(void* const* d_in, const int* in_sizes, int n_in,
                              void* d_out, int out_size, void* d_ws, size_t ws_size,
                              hipStream_t stream) {
    char* base = (char*)d_ws;
    size_t off = 0;
    auto alloc = [&](size_t b) -> void* { void* p = base + off; off += (b + 255) & ~(size_t)255; return p; };

    unsigned short* Xbf   = (unsigned short*)alloc((size_t)MPAD * 256 * 2);  // also reused as r_buf
    unsigned short* h_par = (unsigned short*)alloc((size_t)NPAR * 256 * 2);
    unsigned short* h_fig = (unsigned short*)alloc((size_t)NFIG * 256 * 2);
    unsigned short* h_tab = (unsigned short*)alloc((size_t)NTAB * 256 * 2);
    unsigned short* h_cit = (unsigned short*)alloc((size_t)NCIT * 256 * 2);
    unsigned short* WT_par = (unsigned short*)alloc(256 * 256 * 2);
    unsigned short* WT_fig = (unsigned short*)alloc(256 * 256 * 2);
    unsigned short* WT_tab = (unsigned short*)alloc(256 * 256 * 2);
    unsigned short* WT_cit = (unsigned short*)alloc(256 * 256 * 2);
    unsigned short* kwT    = (unsigned short*)alloc(256 * 256 * 2);
    float* as_pf = (float*)alloc((size_t)NPAR * 8 * 4);
    float* ad_fp = (float*)alloc((size_t)NPAR * 8 * 4);
    float* ad_tp = (float*)alloc((size_t)NPAR * 8 * 4);
    float* ad_cp = (float*)alloc((size_t)NPAR * 8 * 4);
    float* as_fp = (float*)alloc((size_t)NFIG * 8 * 4);
    float* ad_pf = (float*)alloc((size_t)NFIG * 8 * 4);
    float* as_tp = (float*)alloc((size_t)NTAB * 8 * 4);
    float* as_cp = (float*)alloc((size_t)NCIT * 8 * 4);
    float* gbuf  = (float*)alloc((size_t)3 * NPAR * 4);
    int* count   = (int*)alloc((size_t)NPAR * 4);
    int* elist   = (int*)alloc((size_t)NPAR * CAP * 4);
    float* kacc  = (float*)alloc(3 * 256 * 4);
    float* uvec  = (float*)alloc(256 * 4);
    float* vvec  = (float*)alloc(256 * 4);
    float* smallb = (float*)alloc(512 * 4);
    unsigned short* r_buf = Xbf;

    hipMemsetAsync(kacc, 0, 3 * 256 * 4, stream);
    hipMemsetAsync(smallb, 0, 512 * 4, stream);

    k_transpose_bf16<<<256, 256, 0, stream>>>((const float*)d_in[4],  WT_par);
    k_transpose_bf16<<<256, 256, 0, stream>>>((const float*)d_in[6],  WT_fig);
    k_transpose_bf16<<<256, 256, 0, stream>>>((const float*)d_in[8],  WT_tab);
    k_transpose_bf16<<<256, 256, 0, stream>>>((const float*)d_in[10], WT_cit);
    k_transpose_bf16<<<256, 256, 0, stream>>>((const float*)d_in[24], kwT);

    k_precompute<<<1, 256, 0, stream>>>((const float*)d_in[29], (const float*)d_in[30],
                                        (const float*)d_in[27], (const float*)d_in[28],
                                        (const float*)d_in[35], (const float*)d_in[36],
                                        uvec, vvec, smallb);

    // per-type: convert f32->bf16 into Xbf, then MFMA projection
    const float* Xs[4]   = { (const float*)d_in[0], (const float*)d_in[1], (const float*)d_in[2], (const float*)d_in[3] };
    const unsigned short* WTs[4] = { WT_par, WT_fig, WT_tab, WT_cit };
    const float* bps[4]  = { (const float*)d_in[5], (const float*)d_in[7], (const float*)d_in[9], (const float*)d_in[11] };
    unsigned short* hs[4] = { h_par, h_fig, h_tab, h_cit };
    int Ns[4] = { NPAR, NFIG, NTAB, NCIT };
    for (int ty = 0; ty < 4; ++ty) {
        k_cvt<<<2048, 256, 0, stream>>>(Xs[ty], Xbf, Ns[ty] * 64);
        k_gemm_bf16<<<dim3(2, (Ns[ty] + 127) / 128), 256, 0, stream>>>(
            Xbf, WTs[ty], bps[ty], hs[ty], nullptr, Ns[ty], 0);
    }

    k_att<<<25000, 256, 0, stream>>>(h_par, NPAR,
                                     (const float*)d_in[12], as_pf, (const float*)d_in[15], ad_fp,
                                     (const float*)d_in[19], ad_tp, (const float*)d_in[23], ad_cp, 4);
    k_att<<<5000, 256, 0, stream>>>(h_fig, NFIG,
                                    (const float*)d_in[14], as_fp, (const float*)d_in[13], ad_pf,
                                    nullptr, nullptr, nullptr, nullptr, 2);
    k_att<<<5000, 256, 0, stream>>>(h_tab, NTAB,
                                    (const float*)d_in[18], as_tp, nullptr, nullptr,
                                    nullptr, nullptr, nullptr, nullptr, 1);
    k_att<<<12500, 256, 0, stream>>>(h_cit, NCIT,
                                     (const float*)d_in[22], as_cp, nullptr, nullptr,
                                     nullptr, nullptr, nullptr, nullptr, 1);

    k_pf_target<<<256, 256, 0, stream>>>((const int*)d_in[37], (const int*)d_in[38], (const int*)d_in[49],
                                         h_par, as_pf, ad_pf, smallb);

    const int* srcs[3] = { (const int*)d_in[39], (const int*)d_in[43], (const int*)d_in[47] };
    const int* dsts[3] = { (const int*)d_in[40], (const int*)d_in[44], (const int*)d_in[48] };
    const unsigned short* hsrcs[3] = { h_fig, h_tab, h_cit };
    const float* ass[3] = { as_fp, as_tp, as_cp };
    const float* ads[3] = { ad_fp, ad_tp, ad_cp };
    for (int m = 0; m < 3; ++m) {
        hipMemsetAsync(count, 0, (size_t)NPAR * 4, stream);
        k_bucket<<<(NEDGE + 255) / 256, 256, 0, stream>>>(dsts[m], count, elist);
        k_gather<<<25000, 256, 0, stream>>>(srcs[m], count, elist, hsrcs[m], ass[m], ads[m],
                                            r_buf, vvec, gbuf + (size_t)m * NPAR, NPAR);
        k_gemm_bf16<<<dim3(2, 782), 256, 0, stream>>>(
            r_buf, kwT, (const float*)d_in[25], nullptr, kacc + m * 256, NPAR, 1);
    }

    k_finalize<<<1, 256, 0, stream>>>(kacc, (const float*)d_in[26], uvec, smallb);
    k_scores<<<391, 256, 0, stream>>>(gbuf, smallb, (float*)d_out);
}

// Round 3
// 575.352 us; speedup vs baseline: 1.6367x; 1.2736x over previous
//
#include <hip/hip_runtime.h>
#include <hip/hip_bf16.h>
#include <math.h>

typedef float f32x4 __attribute__((ext_vector_type(4)));
typedef short bf16x8 __attribute__((ext_vector_type(8)));

#define NPAR 100000
#define NFIG 20000
#define NTAB 20000
#define NCIT 50000
#define NEDGE 200000
#define CAP 32
#define MPAD 100096   // 782*128
#define PFCAP 79

__device__ __forceinline__ unsigned short f2b(float f) {
    union { float f; unsigned u; } x; x.f = f;
    unsigned r = x.u + 0x7FFFu + ((x.u >> 16) & 1u);
    return (unsigned short)(r >> 16);
}
__device__ __forceinline__ float b2f(unsigned short b) {
    union { unsigned u; float f; } x; x.u = ((unsigned)b) << 16; return x.f;
}
__device__ __forceinline__ float fast_tanh(float x) {
    float e = __expf(2.f * x);
    return 1.f - 2.f * __builtin_amdgcn_rcpf(e + 1.f);
}
__device__ __forceinline__ void async_copy16(const unsigned short* g, unsigned short* l) {
    __builtin_amdgcn_global_load_lds(
        (const __attribute__((address_space(1))) unsigned int*)g,
        (__attribute__((address_space(3))) unsigned int*)l, 16, 0, 0);
}

// ---- 5 weight transposes in one launch: W [256,256] f32 (k,n) -> WT bf16 [n][k] ----
__global__ void k_transpose5(const float* __restrict__ W0, const float* __restrict__ W1,
                             const float* __restrict__ W2, const float* __restrict__ W3,
                             const float* __restrict__ W4, unsigned short* __restrict__ WT) {
    int b = blockIdx.x, which = b >> 8, k = b & 255, n = threadIdx.x;
    const float* W = which == 0 ? W0 : which == 1 ? W1 : which == 2 ? W2 : which == 3 ? W3 : W4;
    WT[(size_t)which * 65536 + n * 256 + k] = f2b(W[k * 256 + n]);
}

// ---- u = Wh_fig @ cls_w1, v = Wh_par @ cls_w2, Cpart ----
__global__ void k_precompute(const float* __restrict__ WhF, const float* __restrict__ bhF,
                             const float* __restrict__ WhP, const float* __restrict__ bhP,
                             const float* __restrict__ clsw, const float* __restrict__ clsb,
                             float* __restrict__ u, float* __restrict__ v, float* __restrict__ smallb) {
    int t = threadIdx.x;
    float su = 0.f, sv = 0.f;
    for (int j = 0; j < 128; ++j) {
        su += WhF[t * 128 + j] * clsw[j];
        sv += WhP[t * 128 + j] * clsw[128 + j];
    }
    u[t] = su; v[t] = sv;
    if (t == 0) {
        float c = clsb[0];
        for (int j = 0; j < 128; ++j) c += bhF[j] * clsw[j] + bhP[j] * clsw[128 + j];
        smallb[264] = c;
    }
}

// ---- projection GEMM with fused f32->bf16 A staging (reg-staged A, gll B, dbuf) ----
__global__ __launch_bounds__(256) void k_gemm_proj(const float* __restrict__ Xf,
                                                   const unsigned short* __restrict__ B,
                                                   const float* __restrict__ bias,
                                                   unsigned short* __restrict__ Hout, int Nrows) {
    __shared__ __align__(16) unsigned short As[2][128 * 32];
    __shared__ __align__(16) unsigned short Bs[2][128 * 32];
    int t = threadIdx.x, l = t & 63, w = t >> 6;
    int n0 = blockIdx.x * 128, m0 = blockIdx.y * 128;
    int wm = (w >> 1) * 64, wn = (w & 1) * 64;
    int lr = l & 15, hi = l >> 4;
    int srow = l >> 2, scol = (l & 3) * 8;
    int arow = t >> 1, acolh = (t & 1) * 16;
    bool aok = (m0 + arow) < Nrows;
    const float* Arow = Xf + (size_t)(m0 + arow) * 256 + acolh;
    const unsigned short* Bbase = B + (size_t)n0 * 256;
    f32x4 acc[4][4] = {};
    float4 a4[4];

    auto loadA = [&](int k0) {
        if (aok) {
            const float4* p = reinterpret_cast<const float4*>(Arow + k0);
            a4[0] = p[0]; a4[1] = p[1]; a4[2] = p[2]; a4[3] = p[3];
        } else {
            a4[0] = a4[1] = a4[2] = a4[3] = make_float4(0.f, 0.f, 0.f, 0.f);
        }
    };
    auto writeA = [&](int buf) {
        unsigned short tmp[16];
#pragma unroll
        for (int i = 0; i < 4; ++i) {
            tmp[i * 4 + 0] = f2b(a4[i].x); tmp[i * 4 + 1] = f2b(a4[i].y);
            tmp[i * 4 + 2] = f2b(a4[i].z); tmp[i * 4 + 3] = f2b(a4[i].w);
        }
        unsigned short* d = &As[buf][arow * 32 + acolh];
        *reinterpret_cast<uint4*>(d) = *reinterpret_cast<const uint4*>(tmp);
        *reinterpret_cast<uint4*>(d + 8) = *reinterpret_cast<const uint4*>(tmp + 8);
    };
    auto stageB = [&](int buf, int k0) {
#pragma unroll
        for (int c = 0; c < 2; ++c) {
            int ci = w * 2 + c;
            async_copy16(Bbase + (size_t)(ci * 16 + srow) * 256 + k0 + scol, &Bs[buf][ci * 512]);
        }
    };

    loadA(0); stageB(0, 0); writeA(0);
    __syncthreads();
    int cur = 0;
    for (int ks = 0; ks < 8; ++ks) {
        if (ks < 7) { loadA((ks + 1) * 32); stageB(cur ^ 1, (ks + 1) * 32); }
        bf16x8 af[4], bfr[4];
#pragma unroll
        for (int mm = 0; mm < 4; ++mm)
            af[mm] = *reinterpret_cast<const bf16x8*>(&As[cur][(wm + mm * 16 + lr) * 32 + hi * 8]);
#pragma unroll
        for (int nn = 0; nn < 4; ++nn)
            bfr[nn] = *reinterpret_cast<const bf16x8*>(&Bs[cur][(wn + nn * 16 + lr) * 32 + hi * 8]);
#pragma unroll
        for (int mm = 0; mm < 4; ++mm)
#pragma unroll
            for (int nn = 0; nn < 4; ++nn)
                acc[mm][nn] = __builtin_amdgcn_mfma_f32_16x16x32_bf16(af[mm], bfr[nn], acc[mm][nn], 0, 0, 0);
        if (ks < 7) writeA(cur ^ 1);
        __syncthreads();
        cur ^= 1;
    }
#pragma unroll
    for (int mm = 0; mm < 4; ++mm)
#pragma unroll
        for (int nn = 0; nn < 4; ++nn) {
            int col = n0 + wn + nn * 16 + lr;
            float bv = bias[col];
#pragma unroll
            for (int r = 0; r < 4; ++r) {
                int row = m0 + wm + mm * 16 + hi * 4 + r;
                if (row < Nrows) Hout[(size_t)row * 256 + col] = f2b(acc[mm][nn][r] + bv);
            }
        }
}

// ---- kmean GEMM: colsum(tanh(A @ B + kb)) -> atomicAdd ksum ; A bf16 via gll ----
__global__ __launch_bounds__(256) void k_gemm_kmean(const unsigned short* __restrict__ A,
                                                    const unsigned short* __restrict__ B,
                                                    const float* __restrict__ bias,
                                                    float* __restrict__ ksum, int Nrows) {
    __shared__ __align__(16) unsigned short As[2][128 * 32];
    __shared__ __align__(16) unsigned short Bs[2][128 * 32];
    int t = threadIdx.x, l = t & 63, w = t >> 6;
    int n0 = blockIdx.x * 128, m0 = blockIdx.y * 128;
    int wm = (w >> 1) * 64, wn = (w & 1) * 64;
    int lr = l & 15, hi = l >> 4;
    int srow = l >> 2, scol = (l & 3) * 8;
    f32x4 acc[4][4] = {};
    const unsigned short* Abase = A + (size_t)m0 * 256;
    const unsigned short* Bbase = B + (size_t)n0 * 256;

    auto stage = [&](int buf, int k0) {
#pragma unroll
        for (int c = 0; c < 2; ++c) {
            int ci = w * 2 + c;
            async_copy16(Abase + (size_t)(ci * 16 + srow) * 256 + k0 + scol, &As[buf][ci * 512]);
            async_copy16(Bbase + (size_t)(ci * 16 + srow) * 256 + k0 + scol, &Bs[buf][ci * 512]);
        }
    };

    stage(0, 0);
    __syncthreads();
    int cur = 0;
    for (int ks = 0; ks < 8; ++ks) {
        if (ks < 7) stage(cur ^ 1, (ks + 1) * 32);
        bf16x8 af[4], bfr[4];
#pragma unroll
        for (int mm = 0; mm < 4; ++mm)
            af[mm] = *reinterpret_cast<const bf16x8*>(&As[cur][(wm + mm * 16 + lr) * 32 + hi * 8]);
#pragma unroll
        for (int nn = 0; nn < 4; ++nn)
            bfr[nn] = *reinterpret_cast<const bf16x8*>(&Bs[cur][(wn + nn * 16 + lr) * 32 + hi * 8]);
#pragma unroll
        for (int mm = 0; mm < 4; ++mm)
#pragma unroll
            for (int nn = 0; nn < 4; ++nn)
                acc[mm][nn] = __builtin_amdgcn_mfma_f32_16x16x32_bf16(af[mm], bfr[nn], acc[mm][nn], 0, 0, 0);
        __syncthreads();
        cur ^= 1;
    }
#pragma unroll
    for (int nn = 0; nn < 4; ++nn) {
        int col = n0 + wn + nn * 16 + lr;
        float kbv = bias[col];
        float cs = 0.f;
#pragma unroll
        for (int mm = 0; mm < 4; ++mm)
#pragma unroll
            for (int r = 0; r < 4; ++r) {
                int row = m0 + wm + mm * 16 + hi * 4 + r;
                if (row < Nrows) cs += fast_tanh(acc[mm][nn][r] + kbv);
            }
        cs += __shfl_xor(cs, 16);
        cs += __shfl_xor(cs, 32);
        if (hi == 0) atomicAdd(&ksum[col], cs);
    }
}

// ---- merged per-node attention dots (4 node types, block-range partitioned) ----
struct AttPack {
    const unsigned short *Hp, *Hf, *Ht, *Hc;
    const float *ap0, *ap1, *ap2, *ap3; float *op0, *op1, *op2, *op3;
    const float *af0, *af1; float *of0, *of1;
    const float *at0; float *ot0;
    const float *ac0; float *oc0;
};
__global__ void k_att_all(AttPack p) {
    int bid = blockIdx.x, w = threadIdx.x >> 6, l = threadIdx.x & 63;
    const unsigned short* H; int N, row, nv;
    const float *A0, *A1 = nullptr, *A2 = nullptr, *A3 = nullptr;
    float *O0, *O1 = nullptr, *O2 = nullptr, *O3 = nullptr;
    if (bid < 25000)      { H = p.Hp; N = NPAR; row = bid * 4 + w; nv = 4;
                            A0 = p.ap0; A1 = p.ap1; A2 = p.ap2; A3 = p.ap3;
                            O0 = p.op0; O1 = p.op1; O2 = p.op2; O3 = p.op3; }
    else if (bid < 30000) { H = p.Hf; N = NFIG; row = (bid - 25000) * 4 + w; nv = 2;
                            A0 = p.af0; A1 = p.af1; O0 = p.of0; O1 = p.of1; }
    else if (bid < 35000) { H = p.Ht; N = NTAB; row = (bid - 30000) * 4 + w; nv = 1;
                            A0 = p.at0; O0 = p.ot0; }
    else                  { H = p.Hc; N = NCIT; row = (bid - 35000) * 4 + w; nv = 1;
                            A0 = p.ac0; O0 = p.oc0; }
    if (row >= N) return;
    ushort4 hv = *reinterpret_cast<const ushort4*>(&H[(size_t)row * 256 + l * 4]);
    float h0 = b2f(hv.x), h1 = b2f(hv.y), h2 = b2f(hv.z), h3 = b2f(hv.w);
    int e0 = l * 4;
#define ATT_DOT(A, O) { \
        float s = h0 * A[e0] + h1 * A[e0 + 1] + h2 * A[e0 + 2] + h3 * A[e0 + 3]; \
        s += __shfl_xor(s, 1); s += __shfl_xor(s, 2); s += __shfl_xor(s, 4); \
        if ((l & 7) == 0) O[row * 8 + (l >> 3)] = s; }
    ATT_DOT(A0, O0);
    if (nv > 1) ATT_DOT(A1, O1);
    if (nv > 2) ATT_DOT(A2, O2);
    if (nv > 3) ATT_DOT(A3, O3);
#undef ATT_DOT
}

// ---- bucket all 3 metapaths in one launch ----
__global__ void k_bucket3(const int* __restrict__ d0, const int* __restrict__ d1,
                          const int* __restrict__ d2, int* __restrict__ count,
                          int* __restrict__ elist) {
    int b = blockIdx.x;
    int m = b / 782;
    int e = (b - m * 782) * 256 + threadIdx.x;
    if (e >= NEDGE) return;
    const int* dst = m == 0 ? d0 : m == 1 ? d1 : d2;
    int d = dst[e];
    int* cnt = count + (size_t)m * NPAR;
    int* el = elist + (size_t)m * NPAR * CAP;
    int slot = atomicAdd(&cnt[d], 1);
    if (slot < CAP) el[(size_t)d * CAP + slot] = e;
}

// ---- per-dst aggregation (one wave per dst), parallel edge-index prefetch ----
__global__ void k_gather(const int* __restrict__ src, const int* __restrict__ count,
                         const int* __restrict__ elist, const unsigned short* __restrict__ Hsrc,
                         const float* __restrict__ as_, const float* __restrict__ ad_,
                         unsigned short* __restrict__ Rout, const float* __restrict__ v,
                         float* __restrict__ gout, int Ndst) {
    int w = threadIdx.x >> 6, l = threadIdx.x & 63;
    int d = blockIdx.x * 4 + w;
    if (d >= Ndst) return;
    int h = l >> 3;
    float adh = ad_[d * 8 + h];
    int cnt = count[d]; if (cnt > CAP) cnt = CAP;
    int s_pre = 0;
    if (l < cnt) s_pre = src[elist[(size_t)d * CAP + l]];
    float a0 = 0.f, a1 = 0.f, a2 = 0.f, a3 = 0.f, den = 0.f;
    for (int i = 0; i < cnt; ++i) {
        int s = __shfl(s_pre, i);
        float al = as_[s * 8 + h] + adh;
        al = al > 0.f ? al : 0.2f * al;
        float ex = __expf(al);
        den += ex;
        ushort4 hv = *reinterpret_cast<const ushort4*>(&Hsrc[(size_t)s * 256 + l * 4]);
        a0 += ex * b2f(hv.x); a1 += ex * b2f(hv.y); a2 += ex * b2f(hv.z); a3 += ex * b2f(hv.w);
    }
    float inv = 1.0f / (den + 1e-16f);
    float r0 = fmaxf(a0 * inv, 0.f), r1 = fmaxf(a1 * inv, 0.f);
    float r2 = fmaxf(a2 * inv, 0.f), r3 = fmaxf(a3 * inv, 0.f);
    ushort4 rv; rv.x = f2b(r0); rv.y = f2b(r1); rv.z = f2b(r2); rv.w = f2b(r3);
    *reinterpret_cast<ushort4*>(&Rout[(size_t)d * 256 + l * 4]) = rv;
    float gs = r0 * v[l * 4] + r1 * v[l * 4 + 1] + r2 * v[l * 4 + 2] + r3 * v[l * 4 + 3];
    gs += __shfl_xor(gs, 1); gs += __shfl_xor(gs, 2); gs += __shfl_xor(gs, 4);
    gs += __shfl_xor(gs, 8); gs += __shfl_xor(gs, 16); gs += __shfl_xor(gs, 32);
    if (l == 0) gout[d] = gs;
}

// ---- pf phase 1: compact matching edges ----
__global__ void k_pf_scan(const int* __restrict__ psrc, const int* __restrict__ pdst,
                          const int* __restrict__ tgtp, int* __restrict__ mlist) {
    int e = blockIdx.x * 256 + threadIdx.x;
    if (e >= NEDGE) return;
    if (pdst[e] == tgtp[0]) {
        int slot = atomicAdd(&mlist[0], 1);
        if (slot < PFCAP) mlist[1 + slot] = psrc[e];
    }
}

// ---- pf phase 2: wave-parallel accumulate over matches (1 block) ----
__global__ void k_pf_acc(const int* __restrict__ mlist, const int* __restrict__ tgtp,
                         const unsigned short* __restrict__ Hpar,
                         const float* __restrict__ as_pf, const float* __restrict__ ad_pf,
                         float* __restrict__ smallb) {
    __shared__ float sacc[4][256];
    __shared__ float sden[4][8];
    int t = threadIdx.x, w = t >> 6, l = t & 63;
    int tgt = tgtp[0];
    int cnt = mlist[0]; if (cnt > PFCAP) cnt = PFCAP;
    int h = l >> 3;
    float adh = ad_pf[tgt * 8 + h];
    float a0 = 0.f, a1 = 0.f, a2 = 0.f, a3 = 0.f, den = 0.f;
    for (int i = w; i < cnt; i += 4) {
        int s = mlist[1 + i];
        float al = as_pf[s * 8 + h] + adh;
        al = al > 0.f ? al : 0.2f * al;
        float ex = __expf(al);
        ushort4 hv = *reinterpret_cast<const ushort4*>(&Hpar[(size_t)s * 256 + l * 4]);
        a0 += ex * b2f(hv.x); a1 += ex * b2f(hv.y); a2 += ex * b2f(hv.z); a3 += ex * b2f(hv.w);
        den += ex;
    }
    sacc[w][l * 4 + 0] = a0; sacc[w][l * 4 + 1] = a1;
    sacc[w][l * 4 + 2] = a2; sacc[w][l * 4 + 3] = a3;
    if ((l & 7) == 0) sden[w][h] = den;
    __syncthreads();
    smallb[t] = sacc[0][t] + sacc[1][t] + sacc[2][t] + sacc[3][t];
    if (t < 8) smallb[256 + t] = sden[0][t] + sden[1][t] + sden[2][t] + sden[3][t];
}

// ---- semantic attention softmax + scalar C ----
__global__ void k_finalize(const float* __restrict__ kacc, const float* __restrict__ q,
                           const float* __restrict__ u, float* __restrict__ smallb) {
    __shared__ float red[256];
    __shared__ float sm[3];
    int t = threadIdx.x;
    float qv = q[t];
    for (int m = 0; m < 3; ++m) {
        red[t] = kacc[m * 256 + t] * qv;
        __syncthreads();
        for (int s = 128; s > 0; s >>= 1) { if (t < s) red[t] += red[t + s]; __syncthreads(); }
        if (t == 0) sm[m] = red[0] / (float)NPAR;
        __syncthreads();
    }
    float den = smallb[256 + (t >> 5)];
    float rt = fmaxf(smallb[t] / (den + 1e-16f), 0.f);
    red[t] = rt * u[t];
    __syncthreads();
    for (int s = 128; s > 0; s >>= 1) { if (t < s) red[t] += red[t + s]; __syncthreads(); }
    if (t == 0) {
        float mx = fmaxf(sm[0], fmaxf(sm[1], sm[2]));
        float e0 = expf(sm[0] - mx), e1 = expf(sm[1] - mx), e2 = expf(sm[2] - mx);
        float sd = e0 + e1 + e2;
        smallb[265] = e0 / sd; smallb[266] = e1 / sd; smallb[267] = e2 / sd;
        smallb[268] = red[0] + smallb[264];
    }
}

// ---- final scores ----
__global__ void k_scores(const float* __restrict__ g, const float* __restrict__ smallb,
                         float* __restrict__ out) {
    int i = blockIdx.x * 256 + threadIdx.x;
    if (i >= NPAR) return;
    out[i] = smallb[268] + smallb[265] * g[i] + smallb[266] * g[NPAR + i] + smallb[267] * g[2 * NPAR + i];
}

extern "C" void kernel_launch(void* const* d_in, const int* in_sizes, int n_in,
                              void* d_out, int out_size, void* d_ws, size_t ws_size,
                              hipStream_t stream) {
    char* base = (char*)d_ws;
    size_t off = 0;
    auto alloc = [&](size_t b) -> void* { void* p = base + off; off += (b + 255) & ~(size_t)255; return p; };

    unsigned short* h_par = (unsigned short*)alloc((size_t)MPAD * 256 * 2);  // reused as r_buf after pf_acc
    unsigned short* h_fig = (unsigned short*)alloc((size_t)NFIG * 256 * 2);
    unsigned short* h_tab = (unsigned short*)alloc((size_t)NTAB * 256 * 2);
    unsigned short* h_cit = (unsigned short*)alloc((size_t)NCIT * 256 * 2);
    unsigned short* WTall = (unsigned short*)alloc((size_t)5 * 65536 * 2);
    unsigned short* WT_par = WTall, *WT_fig = WTall + 65536, *WT_tab = WTall + 2 * 65536,
                  *WT_cit = WTall + 3 * 65536, *kwT = WTall + 4 * 65536;
    float* as_pf = (float*)alloc((size_t)NPAR * 8 * 4);
    float* ad_fp = (float*)alloc((size_t)NPAR * 8 * 4);
    float* ad_tp = (float*)alloc((size_t)NPAR * 8 * 4);
    float* ad_cp = (float*)alloc((size_t)NPAR * 8 * 4);
    float* as_fp = (float*)alloc((size_t)NFIG * 8 * 4);
    float* ad_pf = (float*)alloc((size_t)NFIG * 8 * 4);
    float* as_tp = (float*)alloc((size_t)NTAB * 8 * 4);
    float* as_cp = (float*)alloc((size_t)NCIT * 8 * 4);
    float* gbuf  = (float*)alloc((size_t)3 * NPAR * 4);
    int* count3  = (int*)alloc((size_t)3 * NPAR * 4);
    int* elist3  = (int*)alloc((size_t)3 * NPAR * CAP * 4);
    float* kacc  = (float*)alloc(3 * 256 * 4);       // contiguous scalar block begins
    float* smallb = (float*)alloc(512 * 4);
    int* mlist   = (int*)alloc((1 + PFCAP) * 4);
    float* uvec  = (float*)alloc(256 * 4);
    float* vvec  = (float*)alloc(256 * 4);
    unsigned short* r_buf = h_par;

    // one memset covers kacc(3072B)+smallb(2048B)+mlist(512B padded) = 5632B contiguous
    hipMemsetAsync(kacc, 0, 5632, stream);
    hipMemsetAsync(count3, 0, (size_t)3 * NPAR * 4, stream);

    k_transpose5<<<5 * 256, 256, 0, stream>>>((const float*)d_in[4], (const float*)d_in[6],
                                              (const float*)d_in[8], (const float*)d_in[10],
                                              (const float*)d_in[24], WTall);

    k_precompute<<<1, 256, 0, stream>>>((const float*)d_in[29], (const float*)d_in[30],
                                        (const float*)d_in[27], (const float*)d_in[28],
                                        (const float*)d_in[35], (const float*)d_in[36],
                                        uvec, vvec, smallb);

    k_gemm_proj<<<dim3(2, 782), 256, 0, stream>>>((const float*)d_in[0], WT_par, (const float*)d_in[5],  h_par, NPAR);
    k_gemm_proj<<<dim3(2, 157), 256, 0, stream>>>((const float*)d_in[1], WT_fig, (const float*)d_in[7],  h_fig, NFIG);
    k_gemm_proj<<<dim3(2, 157), 256, 0, stream>>>((const float*)d_in[2], WT_tab, (const float*)d_in[9],  h_tab, NTAB);
    k_gemm_proj<<<dim3(2, 391), 256, 0, stream>>>((const float*)d_in[3], WT_cit, (const float*)d_in[11], h_cit, NCIT);

    AttPack ap;
    ap.Hp = h_par; ap.Hf = h_fig; ap.Ht = h_tab; ap.Hc = h_cit;
    ap.ap0 = (const float*)d_in[12]; ap.op0 = as_pf;
    ap.ap1 = (const float*)d_in[15]; ap.op1 = ad_fp;
    ap.ap2 = (const float*)d_in[19]; ap.op2 = ad_tp;
    ap.ap3 = (const float*)d_in[23]; ap.op3 = ad_cp;
    ap.af0 = (const float*)d_in[14]; ap.of0 = as_fp;
    ap.af1 = (const float*)d_in[13]; ap.of1 = ad_pf;
    ap.at0 = (const float*)d_in[18]; ap.ot0 = as_tp;
    ap.ac0 = (const float*)d_in[22]; ap.oc0 = as_cp;
    k_att_all<<<47500, 256, 0, stream>>>(ap);

    k_pf_scan<<<782, 256, 0, stream>>>((const int*)d_in[37], (const int*)d_in[38],
                                       (const int*)d_in[49], mlist);
    k_pf_acc<<<1, 256, 0, stream>>>(mlist, (const int*)d_in[49], h_par, as_pf, ad_pf, smallb);

    k_bucket3<<<3 * 782, 256, 0, stream>>>((const int*)d_in[40], (const int*)d_in[44],
                                           (const int*)d_in[48], count3, elist3);

    const int* srcs[3] = { (const int*)d_in[39], (const int*)d_in[43], (const int*)d_in[47] };
    const unsigned short* hsrcs[3] = { h_fig, h_tab, h_cit };
    const float* ass[3] = { as_fp, as_tp, as_cp };
    const float* ads[3] = { ad_fp, ad_tp, ad_cp };
    for (int m = 0; m < 3; ++m) {
        k_gather<<<25000, 256, 0, stream>>>(srcs[m], count3 + (size_t)m * NPAR,
                                            elist3 + (size_t)m * NPAR * CAP, hsrcs[m],
                                            ass[m], ads[m], r_buf, vvec,
                                            gbuf + (size_t)m * NPAR, NPAR);
        k_gemm_kmean<<<dim3(2, 782), 256, 0, stream>>>(r_buf, kwT, (const float*)d_in[25],
                                                       kacc + m * 256, NPAR);
    }

    k_finalize<<<1, 256, 0, stream>>>(kacc, (const float*)d_in[26], uvec, smallb);
    k_scores<<<391, 256, 0, stream>>>(gbuf, smallb, (float*)d_out);
}

// Round 4
// 523.206 us; speedup vs baseline: 1.7998x; 1.0997x over previous
//
#include <hip/hip_runtime.h>
#include <hip/hip_bf16.h>
#include <math.h>

typedef float f32x4 __attribute__((ext_vector_type(4)));
typedef short bf16x8 __attribute__((ext_vector_type(8)));

#define NPAR 100000
#define NFIG 20000
#define NTAB 20000
#define NCIT 50000
#define NEDGE 200000
#define CAP 32
#define MPAD 100096   // 782*128
#define PFCAP 79

__device__ __forceinline__ unsigned short f2b(float f) {
    union { float f; unsigned u; } x; x.f = f;
    unsigned r = x.u + 0x7FFFu + ((x.u >> 16) & 1u);
    return (unsigned short)(r >> 16);
}
__device__ __forceinline__ float b2f(unsigned short b) {
    union { unsigned u; float f; } x; x.u = ((unsigned)b) << 16; return x.f;
}
__device__ __forceinline__ float fast_tanh(float x) {
    float e = __expf(2.f * x);
    return 1.f - 2.f * __builtin_amdgcn_rcpf(e + 1.f);
}
__device__ __forceinline__ void async_copy16(const unsigned short* g, unsigned short* l) {
    __builtin_amdgcn_global_load_lds(
        (const __attribute__((address_space(1))) unsigned int*)g,
        (__attribute__((address_space(3))) unsigned int*)l, 16, 0, 0);
}

// ---- 5 weight transposes in one launch: W [256,256] f32 (k,n) -> WT bf16 [n][k] ----
__global__ void k_transpose5(const float* __restrict__ W0, const float* __restrict__ W1,
                             const float* __restrict__ W2, const float* __restrict__ W3,
                             const float* __restrict__ W4, unsigned short* __restrict__ WT) {
    int b = blockIdx.x, which = b >> 8, k = b & 255, n = threadIdx.x;
    const float* W = which == 0 ? W0 : which == 1 ? W1 : which == 2 ? W2 : which == 3 ? W3 : W4;
    WT[(size_t)which * 65536 + n * 256 + k] = f2b(W[k * 256 + n]);
}

// ---- u = Wh_fig @ cls_w1, v = Wh_par @ cls_w2, Cpart ----
__global__ void k_precompute(const float* __restrict__ WhF, const float* __restrict__ bhF,
                             const float* __restrict__ WhP, const float* __restrict__ bhP,
                             const float* __restrict__ clsw, const float* __restrict__ clsb,
                             float* __restrict__ u, float* __restrict__ v, float* __restrict__ smallb) {
    int t = threadIdx.x;
    float su = 0.f, sv = 0.f;
    for (int j = 0; j < 128; ++j) {
        su += WhF[t * 128 + j] * clsw[j];
        sv += WhP[t * 128 + j] * clsw[128 + j];
    }
    u[t] = su; v[t] = sv;
    if (t == 0) {
        float c = clsb[0];
        for (int j = 0; j < 128; ++j) c += bhF[j] * clsw[j] + bhP[j] * clsw[128 + j];
        smallb[264] = c;
    }
}

// ---- merged projection GEMM: 512 thr, tile 128x256, fused f32->bf16 A staging ----
struct ProjPack {
    const float* X[4];
    const unsigned short* WT[4];
    const float* bias[4];
    unsigned short* H[4];
    int nrows[4];
    int bbase[4];   // first block index of each type
};
__global__ __launch_bounds__(512, 4) void k_gemm_proj(ProjPack p) {
    __shared__ __align__(16) unsigned short As[2][128 * 32];   // 16 KB
    __shared__ __align__(16) unsigned short Bs[2][256 * 32];   // 32 KB
    int bid = blockIdx.x;
    int ty = (bid >= p.bbase[1]) + (bid >= p.bbase[2]) + (bid >= p.bbase[3]);
    int m0 = (bid - p.bbase[ty]) * 128;
    const float* Xf = p.X[ty];
    const unsigned short* B = p.WT[ty];
    const float* bias = p.bias[ty];
    unsigned short* Hout = p.H[ty];
    int Nrows = p.nrows[ty];

    int t = threadIdx.x, l = t & 63, w = t >> 6;
    int wm = (w >> 2) * 64, wn = (w & 3) * 64;
    int lr = l & 15, hi = l >> 4;
    // A staging: thread -> (row t>>2, col (t&3)*8), 8 f32 -> 8 bf16 (16 B)
    int arow = t >> 2, acol = (t & 3) * 8;
    bool aok = (m0 + arow) < Nrows;
    const float* Arow = Xf + (size_t)(m0 + arow) * 256 + acol;
    f32x4 acc[4][4] = {};
    float4 a4[2];

    auto loadA = [&](int k0) {
        if (aok) {
            const float4* ptr = reinterpret_cast<const float4*>(Arow + k0);
            a4[0] = ptr[0]; a4[1] = ptr[1];
        } else {
            a4[0] = a4[1] = make_float4(0.f, 0.f, 0.f, 0.f);
        }
    };
    auto writeA = [&](int buf) {
        unsigned short tmp[8];
        tmp[0] = f2b(a4[0].x); tmp[1] = f2b(a4[0].y); tmp[2] = f2b(a4[0].z); tmp[3] = f2b(a4[0].w);
        tmp[4] = f2b(a4[1].x); tmp[5] = f2b(a4[1].y); tmp[6] = f2b(a4[1].z); tmp[7] = f2b(a4[1].w);
        *reinterpret_cast<uint4*>(&As[buf][arow * 32 + acol]) = *reinterpret_cast<const uint4*>(tmp);
    };
    auto stageB = [&](int buf, int k0) {
#pragma unroll
        for (int i = 0; i < 2; ++i) {
            int rowb = w * 32 + i * 16;
            async_copy16(B + (size_t)(rowb + (l >> 2)) * 256 + k0 + (l & 3) * 8,
                         &Bs[buf][rowb * 32]);
        }
    };

    loadA(0); stageB(0, 0); writeA(0);
    __syncthreads();
    int cur = 0;
    for (int ks = 0; ks < 8; ++ks) {
        if (ks < 7) { loadA((ks + 1) * 32); stageB(cur ^ 1, (ks + 1) * 32); }
        bf16x8 af[4], bfr[4];
#pragma unroll
        for (int mm = 0; mm < 4; ++mm)
            af[mm] = *reinterpret_cast<const bf16x8*>(&As[cur][(wm + mm * 16 + lr) * 32 + hi * 8]);
#pragma unroll
        for (int nn = 0; nn < 4; ++nn)
            bfr[nn] = *reinterpret_cast<const bf16x8*>(&Bs[cur][(wn + nn * 16 + lr) * 32 + hi * 8]);
#pragma unroll
        for (int mm = 0; mm < 4; ++mm)
#pragma unroll
            for (int nn = 0; nn < 4; ++nn)
                acc[mm][nn] = __builtin_amdgcn_mfma_f32_16x16x32_bf16(af[mm], bfr[nn], acc[mm][nn], 0, 0, 0);
        if (ks < 7) writeA(cur ^ 1);
        __syncthreads();
        cur ^= 1;
    }
#pragma unroll
    for (int mm = 0; mm < 4; ++mm)
#pragma unroll
        for (int nn = 0; nn < 4; ++nn) {
            int col = wn + nn * 16 + lr;
            float bv = bias[col];
#pragma unroll
            for (int r = 0; r < 4; ++r) {
                int row = m0 + wm + mm * 16 + hi * 4 + r;
                if (row < Nrows) Hout[(size_t)row * 256 + col] = f2b(acc[mm][nn][r] + bv);
            }
        }
}

// ---- kmean GEMM: 512 thr, tile 128x256, A bf16 via gll; colsum(tanh(.+kb)) -> atomic ----
__global__ __launch_bounds__(512, 4) void k_gemm_kmean(const unsigned short* __restrict__ A,
                                                       const unsigned short* __restrict__ B,
                                                       const float* __restrict__ bias,
                                                       float* __restrict__ ksum, int Nrows) {
    __shared__ __align__(16) unsigned short As[2][128 * 32];
    __shared__ __align__(16) unsigned short Bs[2][256 * 32];
    int t = threadIdx.x, l = t & 63, w = t >> 6;
    int m0 = blockIdx.x * 128;
    int wm = (w >> 2) * 64, wn = (w & 3) * 64;
    int lr = l & 15, hi = l >> 4;
    f32x4 acc[4][4] = {};
    const unsigned short* Abase = A + (size_t)m0 * 256;

    auto stage = [&](int buf, int k0) {
        int rowa = w * 16;
        async_copy16(Abase + (size_t)(rowa + (l >> 2)) * 256 + k0 + (l & 3) * 8,
                     &As[buf][rowa * 32]);
#pragma unroll
        for (int i = 0; i < 2; ++i) {
            int rowb = w * 32 + i * 16;
            async_copy16(B + (size_t)(rowb + (l >> 2)) * 256 + k0 + (l & 3) * 8,
                         &Bs[buf][rowb * 32]);
        }
    };

    stage(0, 0);
    __syncthreads();
    int cur = 0;
    for (int ks = 0; ks < 8; ++ks) {
        if (ks < 7) stage(cur ^ 1, (ks + 1) * 32);
        bf16x8 af[4], bfr[4];
#pragma unroll
        for (int mm = 0; mm < 4; ++mm)
            af[mm] = *reinterpret_cast<const bf16x8*>(&As[cur][(wm + mm * 16 + lr) * 32 + hi * 8]);
#pragma unroll
        for (int nn = 0; nn < 4; ++nn)
            bfr[nn] = *reinterpret_cast<const bf16x8*>(&Bs[cur][(wn + nn * 16 + lr) * 32 + hi * 8]);
#pragma unroll
        for (int mm = 0; mm < 4; ++mm)
#pragma unroll
            for (int nn = 0; nn < 4; ++nn)
                acc[mm][nn] = __builtin_amdgcn_mfma_f32_16x16x32_bf16(af[mm], bfr[nn], acc[mm][nn], 0, 0, 0);
        __syncthreads();
        cur ^= 1;
    }
#pragma unroll
    for (int nn = 0; nn < 4; ++nn) {
        int col = wn + nn * 16 + lr;
        float kbv = bias[col];
        float cs = 0.f;
#pragma unroll
        for (int mm = 0; mm < 4; ++mm)
#pragma unroll
            for (int r = 0; r < 4; ++r) {
                int row = m0 + wm + mm * 16 + hi * 4 + r;
                if (row < Nrows) cs += fast_tanh(acc[mm][nn][r] + kbv);
            }
        cs += __shfl_xor(cs, 16);
        cs += __shfl_xor(cs, 32);
        if (hi == 0) atomicAdd(&ksum[col], cs);
    }
}

// ---- merged per-node attention dots (4 node types, block-range partitioned) ----
struct AttPack {
    const unsigned short *Hp, *Hf, *Ht, *Hc;
    const float *ap0, *ap1, *ap2, *ap3; float *op0, *op1, *op2, *op3;
    const float *af0, *af1; float *of0, *of1;
    const float *at0; float *ot0;
    const float *ac0; float *oc0;
};
__global__ void k_att_all(AttPack p) {
    int bid = blockIdx.x, w = threadIdx.x >> 6, l = threadIdx.x & 63;
    const unsigned short* H; int N, row, nv;
    const float *A0, *A1 = nullptr, *A2 = nullptr, *A3 = nullptr;
    float *O0, *O1 = nullptr, *O2 = nullptr, *O3 = nullptr;
    if (bid < 25000)      { H = p.Hp; N = NPAR; row = bid * 4 + w; nv = 4;
                            A0 = p.ap0; A1 = p.ap1; A2 = p.ap2; A3 = p.ap3;
                            O0 = p.op0; O1 = p.op1; O2 = p.op2; O3 = p.op3; }
    else if (bid < 30000) { H = p.Hf; N = NFIG; row = (bid - 25000) * 4 + w; nv = 2;
                            A0 = p.af0; A1 = p.af1; O0 = p.of0; O1 = p.of1; }
    else if (bid < 35000) { H = p.Ht; N = NTAB; row = (bid - 30000) * 4 + w; nv = 1;
                            A0 = p.at0; O0 = p.ot0; }
    else                  { H = p.Hc; N = NCIT; row = (bid - 35000) * 4 + w; nv = 1;
                            A0 = p.ac0; O0 = p.oc0; }
    if (row >= N) return;
    ushort4 hv = *reinterpret_cast<const ushort4*>(&H[(size_t)row * 256 + l * 4]);
    float h0 = b2f(hv.x), h1 = b2f(hv.y), h2 = b2f(hv.z), h3 = b2f(hv.w);
    int e0 = l * 4;
#define ATT_DOT(A, O) { \
        float s = h0 * A[e0] + h1 * A[e0 + 1] + h2 * A[e0 + 2] + h3 * A[e0 + 3]; \
        s += __shfl_xor(s, 1); s += __shfl_xor(s, 2); s += __shfl_xor(s, 4); \
        if ((l & 7) == 0) O[row * 8 + (l >> 3)] = s; }
    ATT_DOT(A0, O0);
    if (nv > 1) ATT_DOT(A1, O1);
    if (nv > 2) ATT_DOT(A2, O2);
    if (nv > 3) ATT_DOT(A3, O3);
#undef ATT_DOT
}

// ---- bucket all 3 metapaths in one launch ----
__global__ void k_bucket3(const int* __restrict__ d0, const int* __restrict__ d1,
                          const int* __restrict__ d2, int* __restrict__ count,
                          int* __restrict__ elist) {
    int b = blockIdx.x;
    int m = b / 782;
    int e = (b - m * 782) * 256 + threadIdx.x;
    if (e >= NEDGE) return;
    const int* dst = m == 0 ? d0 : m == 1 ? d1 : d2;
    int d = dst[e];
    int* cnt = count + (size_t)m * NPAR;
    int* el = elist + (size_t)m * NPAR * CAP;
    int slot = atomicAdd(&cnt[d], 1);
    if (slot < CAP) el[(size_t)d * CAP + slot] = e;
}

// ---- per-dst aggregation (one wave per dst), parallel edge-index prefetch ----
__global__ void k_gather(const int* __restrict__ src, const int* __restrict__ count,
                         const int* __restrict__ elist, const unsigned short* __restrict__ Hsrc,
                         const float* __restrict__ as_, const float* __restrict__ ad_,
                         unsigned short* __restrict__ Rout, const float* __restrict__ v,
                         float* __restrict__ gout, int Ndst) {
    int w = threadIdx.x >> 6, l = threadIdx.x & 63;
    int d = blockIdx.x * 4 + w;
    if (d >= Ndst) return;
    int h = l >> 3;
    float adh = ad_[d * 8 + h];
    int cnt = count[d]; if (cnt > CAP) cnt = CAP;
    int s_pre = 0;
    if (l < cnt) s_pre = src[elist[(size_t)d * CAP + l]];
    float a0 = 0.f, a1 = 0.f, a2 = 0.f, a3 = 0.f, den = 0.f;
    for (int i = 0; i < cnt; ++i) {
        int s = __shfl(s_pre, i);
        float al = as_[s * 8 + h] + adh;
        al = al > 0.f ? al : 0.2f * al;
        float ex = __expf(al);
        den += ex;
        ushort4 hv = *reinterpret_cast<const ushort4*>(&Hsrc[(size_t)s * 256 + l * 4]);
        a0 += ex * b2f(hv.x); a1 += ex * b2f(hv.y); a2 += ex * b2f(hv.z); a3 += ex * b2f(hv.w);
    }
    float inv = 1.0f / (den + 1e-16f);
    float r0 = fmaxf(a0 * inv, 0.f), r1 = fmaxf(a1 * inv, 0.f);
    float r2 = fmaxf(a2 * inv, 0.f), r3 = fmaxf(a3 * inv, 0.f);
    ushort4 rv; rv.x = f2b(r0); rv.y = f2b(r1); rv.z = f2b(r2); rv.w = f2b(r3);
    *reinterpret_cast<ushort4*>(&Rout[(size_t)d * 256 + l * 4]) = rv;
    float gs = r0 * v[l * 4] + r1 * v[l * 4 + 1] + r2 * v[l * 4 + 2] + r3 * v[l * 4 + 3];
    gs += __shfl_xor(gs, 1); gs += __shfl_xor(gs, 2); gs += __shfl_xor(gs, 4);
    gs += __shfl_xor(gs, 8); gs += __shfl_xor(gs, 16); gs += __shfl_xor(gs, 32);
    if (l == 0) gout[d] = gs;
}

// ---- pf phase 1: compact matching edges ----
__global__ void k_pf_scan(const int* __restrict__ psrc, const int* __restrict__ pdst,
                          const int* __restrict__ tgtp, int* __restrict__ mlist) {
    int e = blockIdx.x * 256 + threadIdx.x;
    if (e >= NEDGE) return;
    if (pdst[e] == tgtp[0]) {
        int slot = atomicAdd(&mlist[0], 1);
        if (slot < PFCAP) mlist[1 + slot] = psrc[e];
    }
}

// ---- pf phase 2: wave-parallel accumulate over matches (1 block) ----
__global__ void k_pf_acc(const int* __restrict__ mlist, const int* __restrict__ tgtp,
                         const unsigned short* __restrict__ Hpar,
                         const float* __restrict__ as_pf, const float* __restrict__ ad_pf,
                         float* __restrict__ smallb) {
    __shared__ float sacc[4][256];
    __shared__ float sden[4][8];
    int t = threadIdx.x, w = t >> 6, l = t & 63;
    int tgt = tgtp[0];
    int cnt = mlist[0]; if (cnt > PFCAP) cnt = PFCAP;
    int h = l >> 3;
    float adh = ad_pf[tgt * 8 + h];
    float a0 = 0.f, a1 = 0.f, a2 = 0.f, a3 = 0.f, den = 0.f;
    for (int i = w; i < cnt; i += 4) {
        int s = mlist[1 + i];
        float al = as_pf[s * 8 + h] + adh;
        al = al > 0.f ? al : 0.2f * al;
        float ex = __expf(al);
        ushort4 hv = *reinterpret_cast<const ushort4*>(&Hpar[(size_t)s * 256 + l * 4]);
        a0 += ex * b2f(hv.x); a1 += ex * b2f(hv.y); a2 += ex * b2f(hv.z); a3 += ex * b2f(hv.w);
        den += ex;
    }
    sacc[w][l * 4 + 0] = a0; sacc[w][l * 4 + 1] = a1;
    sacc[w][l * 4 + 2] = a2; sacc[w][l * 4 + 3] = a3;
    if ((l & 7) == 0) sden[w][h] = den;
    __syncthreads();
    smallb[t] = sacc[0][t] + sacc[1][t] + sacc[2][t] + sacc[3][t];
    if (t < 8) smallb[256 + t] = sden[0][t] + sden[1][t] + sden[2][t] + sden[3][t];
}

// ---- semantic attention softmax + scalar C ----
__global__ void k_finalize(const float* __restrict__ kacc, const float* __restrict__ q,
                           const float* __restrict__ u, float* __restrict__ smallb) {
    __shared__ float red[256];
    __shared__ float sm[3];
    int t = threadIdx.x;
    float qv = q[t];
    for (int m = 0; m < 3; ++m) {
        red[t] = kacc[m * 256 + t] * qv;
        __syncthreads();
        for (int s = 128; s > 0; s >>= 1) { if (t < s) red[t] += red[t + s]; __syncthreads(); }
        if (t == 0) sm[m] = red[0] / (float)NPAR;
        __syncthreads();
    }
    float den = smallb[256 + (t >> 5)];
    float rt = fmaxf(smallb[t] / (den + 1e-16f), 0.f);
    red[t] = rt * u[t];
    __syncthreads();
    for (int s = 128; s > 0; s >>= 1) { if (t < s) red[t] += red[t + s]; __syncthreads(); }
    if (t == 0) {
        float mx = fmaxf(sm[0], fmaxf(sm[1], sm[2]));
        float e0 = expf(sm[0] - mx), e1 = expf(sm[1] - mx), e2 = expf(sm[2] - mx);
        float sd = e0 + e1 + e2;
        smallb[265] = e0 / sd; smallb[266] = e1 / sd; smallb[267] = e2 / sd;
        smallb[268] = red[0] + smallb[264];
    }
}

// ---- final scores ----
__global__ void k_scores(const float* __restrict__ g, const float* __restrict__ smallb,
                         float* __restrict__ out) {
    int i = blockIdx.x * 256 + threadIdx.x;
    if (i >= NPAR) return;
    out[i] = smallb[268] + smallb[265] * g[i] + smallb[266] * g[NPAR + i] + smallb[267] * g[2 * NPAR + i];
}

extern "C" void kernel_launch(void* const* d_in, const int* in_sizes, int n_in,
                              void* d_out, int out_size, void* d_ws, size_t ws_size,
                              hipStream_t stream) {
    char* base = (char*)d_ws;
    size_t off = 0;
    auto alloc = [&](size_t b) -> void* { void* p = base + off; off += (b + 255) & ~(size_t)255; return p; };

    unsigned short* h_par = (unsigned short*)alloc((size_t)MPAD * 256 * 2);  // reused as r_buf after pf_acc
    unsigned short* h_fig = (unsigned short*)alloc((size_t)NFIG * 256 * 2);
    unsigned short* h_tab = (unsigned short*)alloc((size_t)NTAB * 256 * 2);
    unsigned short* h_cit = (unsigned short*)alloc((size_t)NCIT * 256 * 2);
    unsigned short* WTall = (unsigned short*)alloc((size_t)5 * 65536 * 2);
    unsigned short* WT_par = WTall, *WT_fig = WTall + 65536, *WT_tab = WTall + 2 * 65536,
                  *WT_cit = WTall + 3 * 65536, *kwT = WTall + 4 * 65536;
    float* as_pf = (float*)alloc((size_t)NPAR * 8 * 4);
    float* ad_fp = (float*)alloc((size_t)NPAR * 8 * 4);
    float* ad_tp = (float*)alloc((size_t)NPAR * 8 * 4);
    float* ad_cp = (float*)alloc((size_t)NPAR * 8 * 4);
    float* as_fp = (float*)alloc((size_t)NFIG * 8 * 4);
    float* ad_pf = (float*)alloc((size_t)NFIG * 8 * 4);
    float* as_tp = (float*)alloc((size_t)NTAB * 8 * 4);
    float* as_cp = (float*)alloc((size_t)NCIT * 8 * 4);
    float* gbuf  = (float*)alloc((size_t)3 * NPAR * 4);
    int* count3  = (int*)alloc((size_t)3 * NPAR * 4);
    int* elist3  = (int*)alloc((size_t)3 * NPAR * CAP * 4);
    float* kacc  = (float*)alloc(3 * 256 * 4);       // contiguous scalar block begins
    float* smallb = (float*)alloc(512 * 4);
    int* mlist   = (int*)alloc((1 + PFCAP) * 4);
    float* uvec  = (float*)alloc(256 * 4);
    float* vvec  = (float*)alloc(256 * 4);
    unsigned short* r_buf = h_par;

    // one memset covers kacc(3072B)+smallb(2048B)+mlist(512B padded) = 5632B contiguous
    hipMemsetAsync(kacc, 0, 5632, stream);
    hipMemsetAsync(count3, 0, (size_t)3 * NPAR * 4, stream);

    k_transpose5<<<5 * 256, 256, 0, stream>>>((const float*)d_in[4], (const float*)d_in[6],
                                              (const float*)d_in[8], (const float*)d_in[10],
                                              (const float*)d_in[24], WTall);

    k_precompute<<<1, 256, 0, stream>>>((const float*)d_in[29], (const float*)d_in[30],
                                        (const float*)d_in[27], (const float*)d_in[28],
                                        (const float*)d_in[35], (const float*)d_in[36],
                                        uvec, vvec, smallb);

    ProjPack pp;
    pp.X[0] = (const float*)d_in[0]; pp.X[1] = (const float*)d_in[1];
    pp.X[2] = (const float*)d_in[2]; pp.X[3] = (const float*)d_in[3];
    pp.WT[0] = WT_par; pp.WT[1] = WT_fig; pp.WT[2] = WT_tab; pp.WT[3] = WT_cit;
    pp.bias[0] = (const float*)d_in[5]; pp.bias[1] = (const float*)d_in[7];
    pp.bias[2] = (const float*)d_in[9]; pp.bias[3] = (const float*)d_in[11];
    pp.H[0] = h_par; pp.H[1] = h_fig; pp.H[2] = h_tab; pp.H[3] = h_cit;
    pp.nrows[0] = NPAR; pp.nrows[1] = NFIG; pp.nrows[2] = NTAB; pp.nrows[3] = NCIT;
    pp.bbase[0] = 0; pp.bbase[1] = 782; pp.bbase[2] = 939; pp.bbase[3] = 1096;
    k_gemm_proj<<<1487, 512, 0, stream>>>(pp);

    AttPack ap;
    ap.Hp = h_par; ap.Hf = h_fig; ap.Ht = h_tab; ap.Hc = h_cit;
    ap.ap0 = (const float*)d_in[12]; ap.op0 = as_pf;
    ap.ap1 = (const float*)d_in[15]; ap.op1 = ad_fp;
    ap.ap2 = (const float*)d_in[19]; ap.op2 = ad_tp;
    ap.ap3 = (const float*)d_in[23]; ap.op3 = ad_cp;
    ap.af0 = (const float*)d_in[14]; ap.of0 = as_fp;
    ap.af1 = (const float*)d_in[13]; ap.of1 = ad_pf;
    ap.at0 = (const float*)d_in[18]; ap.ot0 = as_tp;
    ap.ac0 = (const float*)d_in[22]; ap.oc0 = as_cp;
    k_att_all<<<47500, 256, 0, stream>>>(ap);

    k_pf_scan<<<782, 256, 0, stream>>>((const int*)d_in[37], (const int*)d_in[38],
                                       (const int*)d_in[49], mlist);
    k_pf_acc<<<1, 256, 0, stream>>>(mlist, (const int*)d_in[49], h_par, as_pf, ad_pf, smallb);

    k_bucket3<<<3 * 782, 256, 0, stream>>>((const int*)d_in[40], (const int*)d_in[44],
                                           (const int*)d_in[48], count3, elist3);

    const int* srcs[3] = { (const int*)d_in[39], (const int*)d_in[43], (const int*)d_in[47] };
    const unsigned short* hsrcs[3] = { h_fig, h_tab, h_cit };
    const float* ass[3] = { as_fp, as_tp, as_cp };
    const float* ads[3] = { ad_fp, ad_tp, ad_cp };
    for (int m = 0; m < 3; ++m) {
        k_gather<<<25000, 256, 0, stream>>>(srcs[m], count3 + (size_t)m * NPAR,
                                            elist3 + (size_t)m * NPAR * CAP, hsrcs[m],
                                            ass[m], ads[m], r_buf, vvec,
                                            gbuf + (size_t)m * NPAR, NPAR);
        k_gemm_kmean<<<782, 512, 0, stream>>>(r_buf, kwT, (const float*)d_in[25],
                                              kacc + m * 256, NPAR);
    }

    k_finalize<<<1, 256, 0, stream>>>(kacc, (const float*)d_in[26], uvec, smallb);
    k_scores<<<391, 256, 0, stream>>>(gbuf, smallb, (float*)d_out);
}